// Round 5
// baseline (181.401 us; speedup 1.0000x reference)
//
#include <hip/hip_runtime.h>
#include <hip/hip_bf16.h>

#define SEQ 240
#define HID 4096
#define NH 16
#define HD 256

typedef float f32x4 __attribute__((ext_vector_type(4)));
typedef short s16x8 __attribute__((ext_vector_type(8)));
typedef short s16x4 __attribute__((ext_vector_type(4)));

__device__ __forceinline__ short f2bf(float f) {
    unsigned u = __builtin_bit_cast(unsigned, f);
    unsigned r = u + 0x7FFFu + ((u >> 16) & 1u);
    return (short)(r >> 16);
}

__device__ __forceinline__ s16x8 cvt8(float4 a, float4 b) {
    s16x8 r;
    r[0] = f2bf(a.x); r[1] = f2bf(a.y); r[2] = f2bf(a.z); r[3] = f2bf(a.w);
    r[4] = f2bf(b.x); r[5] = f2bf(b.y); r[6] = f2bf(b.z); r[7] = f2bf(b.w);
    return r;
}

// ---------------------------------------------------------------------------
// Kernel 0: convert inputs f32[240][4096] -> bf16 [256][4096], rows >=240 = 0
// ---------------------------------------------------------------------------
__global__ __launch_bounds__(256) void cvt_kernel(
    const float* __restrict__ in1, const float* __restrict__ in2,
    short* __restrict__ A1, short* __restrict__ A2)
{
    const int i = blockIdx.x * 256 + threadIdx.x;   // chunk of 8 elems
    const float* __restrict__ src = blockIdx.y ? in2 : in1;
    short* __restrict__ dst = blockIdx.y ? A2 : A1;
    const int r = i >> 9;
    const int c = (i & 511) * 8;
    s16x8 v = (s16x8){0,0,0,0,0,0,0,0};
    if (r < SEQ) {
        float4 a = *(const float4*)&src[(size_t)r * HID + c];
        float4 b = *(const float4*)&src[(size_t)r * HID + c + 4];
        v = cvt8(a, b);
    }
    *(s16x8*)&dst[(size_t)r * HID + c] = v;
}

// ---------------------------------------------------------------------------
// Kernel 1: QKV gemm partials — NO LDS, NO BARRIERS.  Pure register stream.
// BM=256 (all rows), BN=64, BK=64 per step, grid (64, 3, KS).
// 4 waves as 2m x 2n; per-wave tile 128x32 (acc[8][2]).
// A (bf16, padded, k-contiguous) loaded directly as MFMA fragments from L2.
// W (f32) loaded as 2x dwordx4 per fragment + in-register cvt to bf16;
// B-loads issued first each step -> deep outstanding HBM queue.
// v (g==2) partials stored TRANSPOSED: pvt[z][n][m].
// ---------------------------------------------------------------------------
__global__ __launch_bounds__(256, 3) void qkv_gemm(
    const short* __restrict__ A1, const short* __restrict__ A2,
    const float* __restrict__ Wq, const float* __restrict__ Wk,
    const float* __restrict__ Wv,
    float* __restrict__ pqk, float* __restrict__ pvt, int KC)
{
    const int g  = blockIdx.y;
    const int z  = blockIdx.z;
    const int nb = blockIdx.x * 64;
    const short* __restrict__ A = (g == 0) ? A1 : A2;
    const float* __restrict__ W = (g == 0) ? Wq : (g == 1) ? Wk : Wv;

    const int tid  = threadIdx.x;
    const int lane = tid & 63;
    const int wave = tid >> 6;
    const int wm   = wave >> 1;   // rows wm*128 .. +127
    const int wn   = wave & 1;    // cols nb + wn*32 .. +31
    const int lr   = lane & 15;
    const int lg   = lane >> 4;

    f32x4 acc[8][2];
    #pragma unroll
    for (int m = 0; m < 8; ++m)
        #pragma unroll
        for (int n = 0; n < 2; ++n)
            acc[m][n] = (f32x4){0.f, 0.f, 0.f, 0.f};

    const short* __restrict__ ap = A + (size_t)(wm * 128 + lr) * HID + lg * 8;
    const float* __restrict__ wp = W + (size_t)(nb + wn * 32 + lr) * HID + lg * 8;

    const int kbase = z * KC;
    const int NIT = KC / 64;

    for (int t = 0; t < NIT; ++t) {
        const int k0 = kbase + t * 64;
        // --- B loads first: 8 x dwordx4 from HBM, all outstanding ---
        float4 b0[2][2], b1[2][2];
        #pragma unroll
        for (int n = 0; n < 2; ++n)
            #pragma unroll
            for (int ks = 0; ks < 2; ++ks) {
                const float* s = wp + (size_t)n * 16 * HID + k0 + ks * 32;
                b0[n][ks] = *(const float4*)s;
                b1[n][ks] = *(const float4*)(s + 4);
            }
        // --- A fragments from L2 + MFMA ---
        #pragma unroll
        for (int ks = 0; ks < 2; ++ks) {
            s16x8 af[8];
            #pragma unroll
            for (int m = 0; m < 8; ++m)
                af[m] = *(const s16x8*)(ap + (size_t)m * 16 * HID + k0 + ks * 32);
            #pragma unroll
            for (int n = 0; n < 2; ++n) {
                const s16x8 bf = cvt8(b0[n][ks], b1[n][ks]);
                #pragma unroll
                for (int m = 0; m < 8; ++m)
                    acc[m][n] = __builtin_amdgcn_mfma_f32_16x16x32_bf16(af[m], bf, acc[m][n], 0, 0, 0);
            }
        }
    }

    if (g == 2) {
        // transposed partial store: pvt[z][n][m]
        float* pout = pvt + (size_t)z * HID * SEQ;
        #pragma unroll
        for (int m = 0; m < 8; ++m) {
            const int row0 = wm * 128 + m * 16 + lg * 4;
            if (row0 >= SEQ) continue;
            #pragma unroll
            for (int n = 0; n < 2; ++n) {
                const int col = nb + wn * 32 + n * 16 + lr;
                float4 o = make_float4(acc[m][n][0], acc[m][n][1], acc[m][n][2], acc[m][n][3]);
                *(float4*)&pout[(size_t)col * SEQ + row0] = o;
            }
        }
    } else {
        float* pout = pqk + (size_t)(z * 2 + g) * SEQ * HID;
        #pragma unroll
        for (int m = 0; m < 8; ++m) {
            const int row0 = wm * 128 + m * 16 + lg * 4;
            if (row0 >= SEQ) continue;
            #pragma unroll
            for (int n = 0; n < 2; ++n) {
                const int col = nb + wn * 32 + n * 16 + lr;
                #pragma unroll
                for (int r = 0; r < 4; ++r)
                    pout[(size_t)(row0 + r) * HID + col] = acc[m][n][r];
            }
        }
    }
}

// ---------------------------------------------------------------------------
// Kernel 2: reduce q/k partials + bias -> bf16 row-major
// ---------------------------------------------------------------------------
__global__ __launch_bounds__(256) void reduce_qk(
    const float* __restrict__ pqk,
    const float* __restrict__ bq, const float* __restrict__ bk,
    short* __restrict__ qb, short* __restrict__ kb, int KS)
{
    const int g   = blockIdx.y;
    const int idx = blockIdx.x * 256 + threadIdx.x;   // f32x4 index
    f32x4 s = (f32x4){0.f, 0.f, 0.f, 0.f};
    for (int z = 0; z < KS; ++z)
        s += *(const f32x4*)&pqk[(size_t)(z * 2 + g) * SEQ * HID + (size_t)idx * 4];
    const int n = (idx * 4) & (HID - 1);
    const float* bias = g ? bk : bq;
    s += *(const f32x4*)&bias[n];
    short* ob = g ? kb : qb;
    s16x4 o = (s16x4){f2bf(s[0]), f2bf(s[1]), f2bf(s[2]), f2bf(s[3])};
    *(s16x4*)&ob[(size_t)idx * 4] = o;
}

// ---------------------------------------------------------------------------
// Kernel 3: reduce transposed v partials + bias -> vtb bf16 [4096][240]
// ---------------------------------------------------------------------------
__global__ __launch_bounds__(256) void reduce_v(
    const float* __restrict__ pvt, const float* __restrict__ bv,
    short* __restrict__ vtb, int KS)
{
    const int idx = blockIdx.x * 256 + threadIdx.x;   // f32x4 index over [4096][240]
    f32x4 s = (f32x4){0.f, 0.f, 0.f, 0.f};
    for (int z = 0; z < KS; ++z)
        s += *(const f32x4*)&pvt[(size_t)z * HID * SEQ + (size_t)idx * 4];
    const int n = idx / 60;                           // 60 f32x4 per 240-row
    const float b = bv[n];
    s16x4 o = (s16x4){f2bf(s[0] + b), f2bf(s[1] + b), f2bf(s[2] + b), f2bf(s[3] + b)};
    *(s16x4*)&vtb[(size_t)idx * 4] = o;
}

// ---------------------------------------------------------------------------
// Kernel 4: scores + softmax.  4 waves/block, jt-split, LDS cross-wave
// softmax combine.  P^T stored bf16: ptb[h][j][i].
// ---------------------------------------------------------------------------
__global__ __launch_bounds__(256) void scores_kernel(
    const short* __restrict__ qb, const short* __restrict__ kb,
    short* __restrict__ ptb)
{
    const int it   = blockIdx.x;     // 0..14
    const int h    = blockIdx.y;     // 0..15
    const int tid  = threadIdx.x;
    const int lane = tid & 63;
    const int w    = tid >> 6;
    const int lr   = lane & 15;
    const int lg   = lane >> 4;
    const int jt0  = w * 4;
    const int NJT  = (w < 3) ? 4 : 3;

    __shared__ float redmax[4][16];
    __shared__ float redsum[4][16];

    f32x4 acc[4];
    #pragma unroll
    for (int j = 0; j < 4; ++j) acc[j] = (f32x4){0.f, 0.f, 0.f, 0.f};

    const int ib = it * 16;
    const short* qrow = &qb[(size_t)(ib + lr) * HID + h * HD + lg * 8];

    for (int d0 = 0; d0 < HD; d0 += 32) {
        s16x8 afr = *(const s16x8*)&qrow[d0];
        #pragma unroll
        for (int j = 0; j < 4; ++j) {
            if (j < NJT) {
                s16x8 bfr = *(const s16x8*)&kb[(size_t)((jt0 + j) * 16 + lr) * HID + h * HD + d0 + lg * 8];
                acc[j] = __builtin_amdgcn_mfma_f32_16x16x32_bf16(afr, bfr, acc[j], 0, 0, 0);
            }
        }
    }

    const float sc = 0.0625f;
    #pragma unroll
    for (int j = 0; j < 4; ++j) acc[j] *= sc;

    // phase 1: wave-local max per i, publish
    #pragma unroll
    for (int r = 0; r < 4; ++r) {
        float mx = -1e30f;
        #pragma unroll
        for (int j = 0; j < 4; ++j) if (j < NJT) mx = fmaxf(mx, acc[j][r]);
        #pragma unroll
        for (int s = 1; s < 16; s <<= 1) mx = fmaxf(mx, __shfl_xor(mx, s, 64));
        if (lr == 0) redmax[w][lg * 4 + r] = mx;
    }
    __syncthreads();
    // phase 2: global max, exp, wave-local sum, publish
    #pragma unroll
    for (int r = 0; r < 4; ++r) {
        const int i = lg * 4 + r;
        float mx = fmaxf(fmaxf(redmax[0][i], redmax[1][i]),
                         fmaxf(redmax[2][i], redmax[3][i]));
        float sum = 0.f;
        #pragma unroll
        for (int j = 0; j < 4; ++j) {
            if (j < NJT) {
                float e = expf(acc[j][r] - mx);
                acc[j][r] = e;
                sum += e;
            }
        }
        #pragma unroll
        for (int s = 1; s < 16; s <<= 1) sum += __shfl_xor(sum, s, 64);
        if (lr == 0) redsum[w][i] = sum;
    }
    __syncthreads();
    // phase 3: normalize + store bf16 (4 consecutive i per lane)
    #pragma unroll
    for (int r = 0; r < 4; ++r) {
        const int i = lg * 4 + r;
        const float inv = 1.f / (redsum[0][i] + redsum[1][i] + redsum[2][i] + redsum[3][i]);
        #pragma unroll
        for (int j = 0; j < 4; ++j) if (j < NJT) acc[j][r] *= inv;
    }
    #pragma unroll
    for (int j = 0; j < 4; ++j) {
        if (j < NJT) {
            const int jj = (jt0 + j) * 16 + lr;
            s16x4 o = (s16x4){f2bf(acc[j][0]), f2bf(acc[j][1]), f2bf(acc[j][2]), f2bf(acc[j][3])};
            *(s16x4*)&ptb[(size_t)(h * SEQ + jj) * SEQ + ib + lg * 4] = o;
        }
    }
}

// ---------------------------------------------------------------------------
// Kernel 5: O = P^T V per head, 4 waves/block jt-split, all-bf16 inputs.
// ---------------------------------------------------------------------------
__global__ __launch_bounds__(256) void pv_kernel(
    const short* __restrict__ ptb, const short* __restrict__ vtb,
    float* __restrict__ out)
{
    const int dt   = blockIdx.x;     // 0..15
    const int h    = blockIdx.y;
    const int tid  = threadIdx.x;
    const int lane = tid & 63;
    const int w    = tid >> 6;
    const int lr   = lane & 15;
    const int lg   = lane >> 4;
    const int NJT  = (w < 3) ? 4 : 3;

    f32x4 acc[4];
    #pragma unroll
    for (int j = 0; j < 4; ++j) acc[j] = (f32x4){0.f, 0.f, 0.f, 0.f};

    const short* vrow = &vtb[(size_t)(h * HD + dt * 16 + lr) * SEQ + lg * 8];

    for (int i0 = 0; i0 < 256; i0 += 32) {
        const bool ok = (i0 + lg * 8) < SEQ;
        s16x8 bfr = (s16x8){0,0,0,0,0,0,0,0};
        if (ok) bfr = *(const s16x8*)&vrow[i0];
        #pragma unroll
        for (int j = 0; j < 4; ++j) {
            if (j < NJT) {
                const int jt = w + j * 4;
                s16x8 afr = (s16x8){0,0,0,0,0,0,0,0};
                if (ok) afr = *(const s16x8*)&ptb[(size_t)(h * SEQ + jt * 16 + lr) * SEQ + i0 + lg * 8];
                acc[j] = __builtin_amdgcn_mfma_f32_16x16x32_bf16(afr, bfr, acc[j], 0, 0, 0);
            }
        }
    }

    #pragma unroll
    for (int j = 0; j < 4; ++j) {
        if (j < NJT) {
            const int jt = w + j * 4;
            #pragma unroll
            for (int r = 0; r < 4; ++r)
                out[(size_t)(jt * 16 + lg * 4 + r) * HID + h * HD + dt * 16 + lr] = acc[j][r];
        }
    }
}

extern "C" void kernel_launch(void* const* d_in, const int* in_sizes, int n_in,
                              void* d_out, int out_size, void* d_ws, size_t ws_size,
                              hipStream_t stream) {
    const float* in1 = (const float*)d_in[0];
    const float* in2 = (const float*)d_in[1];
    const float* Wq  = (const float*)d_in[2];
    const float* bq  = (const float*)d_in[3];
    const float* Wk  = (const float*)d_in[4];
    const float* bk  = (const float*)d_in[5];
    const float* Wv  = (const float*)d_in[6];
    const float* bv  = (const float*)d_in[7];
    float* out = (float*)d_out;

    char* w = (char*)d_ws;
    short* A1  = (short*)w;  w += (size_t)256 * HID * 2;        // 2 MB
    short* A2  = (short*)w;  w += (size_t)256 * HID * 2;        // 2 MB
    short* qb  = (short*)w;  w += (size_t)SEQ * HID * 2;        // 1.97 MB
    short* kb  = (short*)w;  w += (size_t)SEQ * HID * 2;
    short* vtb = (short*)w;  w += (size_t)HID * SEQ * 2;
    short* ptb = (short*)w;  w += (size_t)NH * SEQ * SEQ * 2;   // 1.84 MB
    float* pqk = (float*)w;
    const size_t fixed  = (size_t)(w - (char*)d_ws);
    const size_t perKS  = ((size_t)2 * SEQ * HID + (size_t)HID * SEQ) * sizeof(float); // 11.8 MB

    int KS = 1;
    if (fixed + 4 * perKS <= ws_size)      KS = 4;
    else if (fixed + 2 * perKS <= ws_size) KS = 2;
    const int KC = HID / KS;
    float* pvt = pqk + (size_t)KS * 2 * SEQ * HID;

    cvt_kernel<<<dim3(512, 2), 256, 0, stream>>>(in1, in2, A1, A2);
    qkv_gemm<<<dim3(64, 3, KS), 256, 0, stream>>>(A1, A2, Wq, Wk, Wv, pqk, pvt, KC);
    reduce_qk<<<dim3(960, 2), 256, 0, stream>>>(pqk, bq, bk, qb, kb, KS);
    reduce_v<<<960, 256, 0, stream>>>(pvt, bv, vtb, KS);
    scores_kernel<<<dim3(15, 16), 256, 0, stream>>>(qb, kb, ptb);
    pv_kernel<<<dim3(16, 16), 256, 0, stream>>>(ptb, vtb, out);
}

// Round 6
// 157.725 us; speedup vs baseline: 1.1501x; 1.1501x over previous
//
#include <hip/hip_runtime.h>
#include <hip/hip_bf16.h>

#define SEQ 240
#define HID 4096
#define NH 16
#define HD 256

typedef float f32x4 __attribute__((ext_vector_type(4)));
typedef short s16x8 __attribute__((ext_vector_type(8)));
typedef short s16x4 __attribute__((ext_vector_type(4)));

__device__ __forceinline__ short f2bf(float f) {
    unsigned u = __builtin_bit_cast(unsigned, f);
    unsigned r = u + 0x7FFFu + ((u >> 16) & 1u);
    return (short)(r >> 16);
}

__device__ __forceinline__ s16x8 cvt8(float4 a, float4 b) {
    s16x8 r;
    r[0] = f2bf(a.x); r[1] = f2bf(a.y); r[2] = f2bf(a.z); r[3] = f2bf(a.w);
    r[4] = f2bf(b.x); r[5] = f2bf(b.y); r[6] = f2bf(b.z); r[7] = f2bf(b.w);
    return r;
}

// ---------------------------------------------------------------------------
// Kernel 0: convert inputs f32[240][4096] -> bf16 [256][4096], rows >=240 = 0
// ---------------------------------------------------------------------------
__global__ __launch_bounds__(256) void cvt_kernel(
    const float* __restrict__ in1, const float* __restrict__ in2,
    short* __restrict__ A1, short* __restrict__ A2)
{
    const int i = blockIdx.x * 256 + threadIdx.x;   // chunk of 8 elems
    const float* __restrict__ src = blockIdx.y ? in2 : in1;
    short* __restrict__ dst = blockIdx.y ? A2 : A1;
    const int r = i >> 9;
    const int c = (i & 511) * 8;
    s16x8 v = (s16x8){0,0,0,0,0,0,0,0};
    if (r < SEQ) {
        float4 a = *(const float4*)&src[(size_t)r * HID + c];
        float4 b = *(const float4*)&src[(size_t)r * HID + c + 4];
        v = cvt8(a, b);
    }
    *(s16x8*)&dst[(size_t)r * HID + c] = v;
}

// ---------------------------------------------------------------------------
// Kernel 1: QKV gemm partials — HYBRID.
// W (HBM stream): reg-staged prefetch -> double-buffered LDS (8 KB total).
// A (L2-resident bf16, exact fragment layout): direct global loads, no LDS.
// BM=256, BN=32, BK=64, grid (128, 3, KS) = 1536 blocks @ KS=4.
// 4 waves as 4m x 1n; per-wave tile 64x32 (acc[4][2]).
// v (g==2) partials stored TRANSPOSED: pvt[z][n][m].
// ---------------------------------------------------------------------------
__global__ __launch_bounds__(256, 4) void qkv_gemm(
    const short* __restrict__ A1, const short* __restrict__ A2,
    const float* __restrict__ Wq, const float* __restrict__ Wk,
    const float* __restrict__ Wv,
    float* __restrict__ pqk, float* __restrict__ pvt, int KC)
{
    const int g  = blockIdx.y;
    const int z  = blockIdx.z;
    const int nb = blockIdx.x * 32;
    const short* __restrict__ A = (g == 0) ? A1 : A2;
    const float* __restrict__ W = (g == 0) ? Wq : (g == 1) ? Wk : Wv;

    const int tid  = threadIdx.x;
    const int lane = tid & 63;
    const int wm   = tid >> 6;    // wave = m-quarter: rows wm*64 .. +63
    const int lr   = lane & 15;
    const int lg   = lane >> 4;

    __shared__ short Bs[2][32 * 64];    // 2 x 4 KB

    f32x4 acc[4][2];
    #pragma unroll
    for (int m = 0; m < 4; ++m)
        #pragma unroll
        for (int n = 0; n < 2; ++n)
            acc[m][n] = (f32x4){0.f, 0.f, 0.f, 0.f};

    const int brow = tid >> 3;   // 0..31
    const int bsl  = tid & 7;    // 16B slot (8 floats) within 64-col row

    float4 rb0, rb1;
    const float* __restrict__ wsrc = &W[(size_t)(nb + brow) * HID + bsl * 8];
    const short* __restrict__ ap   = A + (size_t)(wm * 64 + lr) * HID + lg * 8;

    const int kbase = z * KC;
    const int NIT = KC / 64;

    auto LOADT = [&](int k0) {
        rb0 = *(const float4*)(wsrc + k0);
        rb1 = *(const float4*)(wsrc + k0 + 4);
    };
    auto STORET = [&](int b) {
        *(s16x8*)&Bs[b][brow * 64 + ((bsl * 8) ^ ((brow & 7) << 3))] = cvt8(rb0, rb1);
    };

    LOADT(kbase);
    STORET(0);
    __syncthreads();

    for (int it = 0; it < NIT; ++it) {
        if (it + 1 < NIT) LOADT(kbase + (it + 1) * 64);   // W prefetch in flight
        const int b = it & 1;
        const int k0 = kbase + it * 64;
        #pragma unroll
        for (int ks = 0; ks < 2; ++ks) {
            const int colx = ks * 32 + lg * 8;
            s16x8 af[4], bf[2];
            #pragma unroll
            for (int m = 0; m < 4; ++m)
                af[m] = *(const s16x8*)(ap + (size_t)m * 16 * HID + k0 + ks * 32);
            #pragma unroll
            for (int n = 0; n < 2; ++n) {
                const int r = n * 16 + lr;
                bf[n] = *(const s16x8*)&Bs[b][r * 64 + (colx ^ ((r & 7) << 3))];
            }
            #pragma unroll
            for (int m = 0; m < 4; ++m)
                #pragma unroll
                for (int n = 0; n < 2; ++n)
                    acc[m][n] = __builtin_amdgcn_mfma_f32_16x16x32_bf16(af[m], bf[n], acc[m][n], 0, 0, 0);
        }
        __syncthreads();                       // all reads of buf b done
        if (it + 1 < NIT) {
            STORET((it + 1) & 1);
            __syncthreads();                   // writes visible before next compute
        }
    }

    if (g == 2) {
        // transposed partial store: pvt[z][n][m]
        float* pout = pvt + (size_t)z * HID * SEQ;
        #pragma unroll
        for (int m = 0; m < 4; ++m) {
            const int row0 = wm * 64 + m * 16 + lg * 4;
            if (row0 >= SEQ) continue;
            #pragma unroll
            for (int n = 0; n < 2; ++n) {
                const int col = nb + n * 16 + lr;
                float4 o = make_float4(acc[m][n][0], acc[m][n][1], acc[m][n][2], acc[m][n][3]);
                *(float4*)&pout[(size_t)col * SEQ + row0] = o;
            }
        }
    } else {
        float* pout = pqk + (size_t)(z * 2 + g) * SEQ * HID;
        #pragma unroll
        for (int m = 0; m < 4; ++m) {
            const int row0 = wm * 64 + m * 16 + lg * 4;
            if (row0 >= SEQ) continue;
            #pragma unroll
            for (int n = 0; n < 2; ++n) {
                const int col = nb + n * 16 + lr;
                #pragma unroll
                for (int r = 0; r < 4; ++r)
                    pout[(size_t)(row0 + r) * HID + col] = acc[m][n][r];
            }
        }
    }
}

// ---------------------------------------------------------------------------
// Kernel 2: reduce q/k partials + bias -> bf16 row-major
// ---------------------------------------------------------------------------
__global__ __launch_bounds__(256) void reduce_qk(
    const float* __restrict__ pqk,
    const float* __restrict__ bq, const float* __restrict__ bk,
    short* __restrict__ qb, short* __restrict__ kb, int KS)
{
    const int g   = blockIdx.y;
    const int idx = blockIdx.x * 256 + threadIdx.x;   // f32x4 index
    f32x4 s = (f32x4){0.f, 0.f, 0.f, 0.f};
    for (int z = 0; z < KS; ++z)
        s += *(const f32x4*)&pqk[(size_t)(z * 2 + g) * SEQ * HID + (size_t)idx * 4];
    const int n = (idx * 4) & (HID - 1);
    const float* bias = g ? bk : bq;
    s += *(const f32x4*)&bias[n];
    short* ob = g ? kb : qb;
    s16x4 o = (s16x4){f2bf(s[0]), f2bf(s[1]), f2bf(s[2]), f2bf(s[3])};
    *(s16x4*)&ob[(size_t)idx * 4] = o;
}

// ---------------------------------------------------------------------------
// Kernel 3: reduce transposed v partials + bias -> vtb bf16 [4096][240]
// ---------------------------------------------------------------------------
__global__ __launch_bounds__(256) void reduce_v(
    const float* __restrict__ pvt, const float* __restrict__ bv,
    short* __restrict__ vtb, int KS)
{
    const int idx = blockIdx.x * 256 + threadIdx.x;   // f32x4 index over [4096][240]
    f32x4 s = (f32x4){0.f, 0.f, 0.f, 0.f};
    for (int z = 0; z < KS; ++z)
        s += *(const f32x4*)&pvt[(size_t)z * HID * SEQ + (size_t)idx * 4];
    const int n = idx / 60;                           // 60 f32x4 per 240-row
    const float b = bv[n];
    s16x4 o = (s16x4){f2bf(s[0] + b), f2bf(s[1] + b), f2bf(s[2] + b), f2bf(s[3] + b)};
    *(s16x4*)&vtb[(size_t)idx * 4] = o;
}

// ---------------------------------------------------------------------------
// Kernel 4: scores + softmax.  4 waves/block, jt-split, LDS cross-wave
// softmax combine.  P^T stored bf16: ptb[h][j][i].
// ---------------------------------------------------------------------------
__global__ __launch_bounds__(256) void scores_kernel(
    const short* __restrict__ qb, const short* __restrict__ kb,
    short* __restrict__ ptb)
{
    const int it   = blockIdx.x;     // 0..14
    const int h    = blockIdx.y;     // 0..15
    const int tid  = threadIdx.x;
    const int lane = tid & 63;
    const int w    = tid >> 6;
    const int lr   = lane & 15;
    const int lg   = lane >> 4;
    const int jt0  = w * 4;
    const int NJT  = (w < 3) ? 4 : 3;

    __shared__ float redmax[4][16];
    __shared__ float redsum[4][16];

    f32x4 acc[4];
    #pragma unroll
    for (int j = 0; j < 4; ++j) acc[j] = (f32x4){0.f, 0.f, 0.f, 0.f};

    const int ib = it * 16;
    const short* qrow = &qb[(size_t)(ib + lr) * HID + h * HD + lg * 8];

    for (int d0 = 0; d0 < HD; d0 += 32) {
        s16x8 afr = *(const s16x8*)&qrow[d0];
        #pragma unroll
        for (int j = 0; j < 4; ++j) {
            if (j < NJT) {
                s16x8 bfr = *(const s16x8*)&kb[(size_t)((jt0 + j) * 16 + lr) * HID + h * HD + d0 + lg * 8];
                acc[j] = __builtin_amdgcn_mfma_f32_16x16x32_bf16(afr, bfr, acc[j], 0, 0, 0);
            }
        }
    }

    const float sc = 0.0625f;
    #pragma unroll
    for (int j = 0; j < 4; ++j) acc[j] *= sc;

    // phase 1: wave-local max per i, publish
    #pragma unroll
    for (int r = 0; r < 4; ++r) {
        float mx = -1e30f;
        #pragma unroll
        for (int j = 0; j < 4; ++j) if (j < NJT) mx = fmaxf(mx, acc[j][r]);
        #pragma unroll
        for (int s = 1; s < 16; s <<= 1) mx = fmaxf(mx, __shfl_xor(mx, s, 64));
        if (lr == 0) redmax[w][lg * 4 + r] = mx;
    }
    __syncthreads();
    // phase 2: global max, exp, wave-local sum, publish
    #pragma unroll
    for (int r = 0; r < 4; ++r) {
        const int i = lg * 4 + r;
        float mx = fmaxf(fmaxf(redmax[0][i], redmax[1][i]),
                         fmaxf(redmax[2][i], redmax[3][i]));
        float sum = 0.f;
        #pragma unroll
        for (int j = 0; j < 4; ++j) {
            if (j < NJT) {
                float e = expf(acc[j][r] - mx);
                acc[j][r] = e;
                sum += e;
            }
        }
        #pragma unroll
        for (int s = 1; s < 16; s <<= 1) sum += __shfl_xor(sum, s, 64);
        if (lr == 0) redsum[w][i] = sum;
    }
    __syncthreads();
    // phase 3: normalize + store bf16 (4 consecutive i per lane)
    #pragma unroll
    for (int r = 0; r < 4; ++r) {
        const int i = lg * 4 + r;
        const float inv = 1.f / (redsum[0][i] + redsum[1][i] + redsum[2][i] + redsum[3][i]);
        #pragma unroll
        for (int j = 0; j < 4; ++j) if (j < NJT) acc[j][r] *= inv;
    }
    #pragma unroll
    for (int j = 0; j < 4; ++j) {
        if (j < NJT) {
            const int jj = (jt0 + j) * 16 + lr;
            s16x4 o = (s16x4){f2bf(acc[j][0]), f2bf(acc[j][1]), f2bf(acc[j][2]), f2bf(acc[j][3])};
            *(s16x4*)&ptb[(size_t)(h * SEQ + jj) * SEQ + ib + lg * 4] = o;
        }
    }
}

// ---------------------------------------------------------------------------
// Kernel 5: O = P^T V per head, 4 waves/block jt-split, all-bf16 inputs.
// ---------------------------------------------------------------------------
__global__ __launch_bounds__(256) void pv_kernel(
    const short* __restrict__ ptb, const short* __restrict__ vtb,
    float* __restrict__ out)
{
    const int dt   = blockIdx.x;     // 0..15
    const int h    = blockIdx.y;
    const int tid  = threadIdx.x;
    const int lane = tid & 63;
    const int w    = tid >> 6;
    const int lr   = lane & 15;
    const int lg   = lane >> 4;
    const int NJT  = (w < 3) ? 4 : 3;

    f32x4 acc[4];
    #pragma unroll
    for (int j = 0; j < 4; ++j) acc[j] = (f32x4){0.f, 0.f, 0.f, 0.f};

    const short* vrow = &vtb[(size_t)(h * HD + dt * 16 + lr) * SEQ + lg * 8];

    for (int i0 = 0; i0 < 256; i0 += 32) {
        const bool ok = (i0 + lg * 8) < SEQ;
        s16x8 bfr = (s16x8){0,0,0,0,0,0,0,0};
        if (ok) bfr = *(const s16x8*)&vrow[i0];
        #pragma unroll
        for (int j = 0; j < 4; ++j) {
            if (j < NJT) {
                const int jt = w + j * 4;
                s16x8 afr = (s16x8){0,0,0,0,0,0,0,0};
                if (ok) afr = *(const s16x8*)&ptb[(size_t)(h * SEQ + jt * 16 + lr) * SEQ + i0 + lg * 8];
                acc[j] = __builtin_amdgcn_mfma_f32_16x16x32_bf16(afr, bfr, acc[j], 0, 0, 0);
            }
        }
    }

    #pragma unroll
    for (int j = 0; j < 4; ++j) {
        if (j < NJT) {
            const int jt = w + j * 4;
            #pragma unroll
            for (int r = 0; r < 4; ++r)
                out[(size_t)(jt * 16 + lg * 4 + r) * HID + h * HD + dt * 16 + lr] = acc[j][r];
        }
    }
}

extern "C" void kernel_launch(void* const* d_in, const int* in_sizes, int n_in,
                              void* d_out, int out_size, void* d_ws, size_t ws_size,
                              hipStream_t stream) {
    const float* in1 = (const float*)d_in[0];
    const float* in2 = (const float*)d_in[1];
    const float* Wq  = (const float*)d_in[2];
    const float* bq  = (const float*)d_in[3];
    const float* Wk  = (const float*)d_in[4];
    const float* bk  = (const float*)d_in[5];
    const float* Wv  = (const float*)d_in[6];
    const float* bv  = (const float*)d_in[7];
    float* out = (float*)d_out;

    char* w = (char*)d_ws;
    short* A1  = (short*)w;  w += (size_t)256 * HID * 2;        // 2 MB
    short* A2  = (short*)w;  w += (size_t)256 * HID * 2;        // 2 MB
    short* qb  = (short*)w;  w += (size_t)SEQ * HID * 2;        // 1.97 MB
    short* kb  = (short*)w;  w += (size_t)SEQ * HID * 2;
    short* vtb = (short*)w;  w += (size_t)HID * SEQ * 2;
    short* ptb = (short*)w;  w += (size_t)NH * SEQ * SEQ * 2;   // 1.84 MB
    float* pqk = (float*)w;
    const size_t fixed  = (size_t)(w - (char*)d_ws);
    const size_t perKS  = ((size_t)2 * SEQ * HID + (size_t)HID * SEQ) * sizeof(float); // 11.8 MB

    int KS = 1;
    if (fixed + 4 * perKS <= ws_size)      KS = 4;
    else if (fixed + 2 * perKS <= ws_size) KS = 2;
    const int KC = HID / KS;
    float* pvt = pqk + (size_t)KS * 2 * SEQ * HID;

    cvt_kernel<<<dim3(512, 2), 256, 0, stream>>>(in1, in2, A1, A2);
    qkv_gemm<<<dim3(128, 3, KS), 256, 0, stream>>>(A1, A2, Wq, Wk, Wv, pqk, pvt, KC);
    reduce_qk<<<dim3(960, 2), 256, 0, stream>>>(pqk, bq, bk, qb, kb, KS);
    reduce_v<<<960, 256, 0, stream>>>(pvt, bv, vtb, KS);
    scores_kernel<<<dim3(15, 16), 256, 0, stream>>>(qb, kb, ptb);
    pv_kernel<<<dim3(16, 16), 256, 0, stream>>>(ptb, vtb, out);
}

// Round 7
// 100.402 us; speedup vs baseline: 1.8067x; 1.5709x over previous
//
#include <hip/hip_runtime.h>
#include <hip/hip_bf16.h>

#define SEQ 240
#define HID 4096
#define NH 16
#define HD 256

typedef float f32x4 __attribute__((ext_vector_type(4)));
typedef short s16x8 __attribute__((ext_vector_type(8)));
typedef short s16x4 __attribute__((ext_vector_type(4)));

__device__ __forceinline__ short f2bf(float f) {
    unsigned u = __builtin_bit_cast(unsigned, f);
    unsigned r = u + 0x7FFFu + ((u >> 16) & 1u);
    return (short)(r >> 16);
}

__device__ __forceinline__ s16x8 cvt8(float4 a, float4 b) {
    s16x8 r;
    r[0] = f2bf(a.x); r[1] = f2bf(a.y); r[2] = f2bf(a.z); r[3] = f2bf(a.w);
    r[4] = f2bf(b.x); r[5] = f2bf(b.y); r[6] = f2bf(b.z); r[7] = f2bf(b.w);
    return r;
}

// swizzled offset (in shorts) for a [128 rows][32 cols] bf16 LDS tile.
// macro-row = r>>1 (128B lines, full bank wrap), slot = ((r&1)*4 + c8) ^ (mrow&7).
// Reads (16 lanes, same c8, consecutive rows): <=2 lanes per 16B slot => free.
__device__ __forceinline__ int swz(int r, int c8) {
    return (r >> 1) * 64 + (((((r & 1) << 2) | c8) ^ ((r >> 1) & 7)) << 3);
}

// ---------------------------------------------------------------------------
// Kernel 0: convert inputs f32[240][4096] -> bf16 [256][4096], rows >=240 = 0
// ---------------------------------------------------------------------------
__global__ __launch_bounds__(256) void cvt_kernel(
    const float* __restrict__ in1, const float* __restrict__ in2,
    short* __restrict__ A1, short* __restrict__ A2)
{
    const int i = blockIdx.x * 256 + threadIdx.x;   // chunk of 8 elems
    const float* __restrict__ src = blockIdx.y ? in2 : in1;
    short* __restrict__ dst = blockIdx.y ? A2 : A1;
    const int r = i >> 9;
    const int c = (i & 511) * 8;
    s16x8 v = (s16x8){0,0,0,0,0,0,0,0};
    if (r < SEQ) {
        float4 a = *(const float4*)&src[(size_t)r * HID + c];
        float4 b = *(const float4*)&src[(size_t)r * HID + c + 4];
        v = cvt8(a, b);
    }
    *(s16x8*)&dst[(size_t)r * HID + c] = v;
}

// ---------------------------------------------------------------------------
// Kernel 1: QKV gemm partials.  BM=128, BN=128, BK=32, KS split-K.
// grid (32, 6, KS): y = mt*3 + g.  768 blocks @ KS=4 = exactly 3/CU.
// 4 waves as 2m x 2n, wave-tile 64x64, acc[4][4]: 8 ds_read_b128 / 16 MFMA.
// Reg-staged prefetch 2 tiles deep; SINGLE barrier per K-step:
//   COMPUTE(b); STORET(b^1) <- regs(t+1); LOADT(t+2); barrier.
// W (f32) converted to bf16 in registers during STORET.
// v (g==2) partials stored TRANSPOSED: pvt[z][n][m].
// ---------------------------------------------------------------------------
__global__ __launch_bounds__(256, 3) void qkv_gemm(
    const short* __restrict__ A1, const short* __restrict__ A2,
    const float* __restrict__ Wq, const float* __restrict__ Wk,
    const float* __restrict__ Wv,
    float* __restrict__ pqk, float* __restrict__ pvt, int KC)
{
    const int g  = blockIdx.y % 3;
    const int mt = blockIdx.y / 3;     // 0..1
    const int z  = blockIdx.z;
    const int nb = blockIdx.x * 128;
    const int mb = mt * 128;
    const short* __restrict__ A = (g == 0) ? A1 : A2;
    const float* __restrict__ W = (g == 0) ? Wq : (g == 1) ? Wk : Wv;

    const int tid  = threadIdx.x;
    const int lane = tid & 63;
    const int wave = tid >> 6;
    const int wm   = wave >> 1;
    const int wn   = wave & 1;
    const int lr   = lane & 15;
    const int lg   = lane >> 4;

    __shared__ short As[2][128 * 32];   // 2 x 8 KB
    __shared__ short Bs[2][128 * 32];   // 2 x 8 KB

    f32x4 acc[4][4];
    #pragma unroll
    for (int m = 0; m < 4; ++m)
        #pragma unroll
        for (int n = 0; n < 4; ++n)
            acc[m][n] = (f32x4){0.f, 0.f, 0.f, 0.f};

    const int srow = tid >> 2;   // 0..63 (+64)
    const int sc8  = tid & 3;    // 8-col group within the 32-wide K slab

    s16x8  ra[2];
    float4 rw0[2], rw1[2];

    const short* __restrict__ asrc = &A[(size_t)(mb + srow) * HID + sc8 * 8];
    const float* __restrict__ wsrc = &W[(size_t)(nb + srow) * HID + sc8 * 8];

    const int kbase = z * KC;
    const int NIT = KC / 32;

    auto LOADT = [&](int k0) {
        #pragma unroll
        for (int p = 0; p < 2; ++p) {
            ra[p]  = *(const s16x8*)(asrc + (size_t)p * 64 * HID + k0);
            const float* s = wsrc + (size_t)p * 64 * HID + k0;
            rw0[p] = *(const float4*)s;
            rw1[p] = *(const float4*)(s + 4);
        }
    };
    auto STORET = [&](int b) {
        #pragma unroll
        for (int p = 0; p < 2; ++p) {
            const int r = srow + p * 64;
            *(s16x8*)&As[b][swz(r, sc8)] = ra[p];
            *(s16x8*)&Bs[b][swz(r, sc8)] = cvt8(rw0[p], rw1[p]);
        }
    };

    LOADT(kbase);
    STORET(0);
    if (NIT > 1) LOADT(kbase + 32);
    __syncthreads();

    for (int it = 0; it < NIT; ++it) {
        const int b = it & 1;
        // COMPUTE tile it from buf b
        s16x8 af[4], bf[4];
        #pragma unroll
        for (int m = 0; m < 4; ++m)
            af[m] = *(const s16x8*)&As[b][swz(wm * 64 + m * 16 + lr, lg)];
        #pragma unroll
        for (int n = 0; n < 4; ++n)
            bf[n] = *(const s16x8*)&Bs[b][swz(wn * 64 + n * 16 + lr, lg)];
        #pragma unroll
        for (int m = 0; m < 4; ++m)
            #pragma unroll
            for (int n = 0; n < 4; ++n)
                acc[m][n] = __builtin_amdgcn_mfma_f32_16x16x32_bf16(af[m], bf[n], acc[m][n], 0, 0, 0);

        if (it + 1 < NIT) {
            STORET(b ^ 1);                          // tile it+1 regs -> other buffer
            if (it + 2 < NIT) LOADT(kbase + (it + 2) * 32);
            __syncthreads();                        // stores visible before next compute
        }
    }

    if (g == 2) {
        // transposed partial store: pvt[z][n][m]
        float* pout = pvt + (size_t)z * HID * SEQ;
        #pragma unroll
        for (int m = 0; m < 4; ++m) {
            const int row0 = mb + wm * 64 + m * 16 + lg * 4;
            if (row0 >= SEQ) continue;
            #pragma unroll
            for (int n = 0; n < 4; ++n) {
                const int col = nb + wn * 64 + n * 16 + lr;
                float4 o = make_float4(acc[m][n][0], acc[m][n][1], acc[m][n][2], acc[m][n][3]);
                *(float4*)&pout[(size_t)col * SEQ + row0] = o;
            }
        }
    } else {
        float* pout = pqk + (size_t)(z * 2 + g) * SEQ * HID;
        #pragma unroll
        for (int m = 0; m < 4; ++m) {
            const int row0 = mb + wm * 64 + m * 16 + lg * 4;
            if (row0 >= SEQ) continue;
            #pragma unroll
            for (int n = 0; n < 4; ++n) {
                const int col = nb + wn * 64 + n * 16 + lr;
                #pragma unroll
                for (int r = 0; r < 4; ++r)
                    pout[(size_t)(row0 + r) * HID + col] = acc[m][n][r];
            }
        }
    }
}

// ---------------------------------------------------------------------------
// Kernel 2: reduce q/k partials + bias -> bf16 row-major
// ---------------------------------------------------------------------------
__global__ __launch_bounds__(256) void reduce_qk(
    const float* __restrict__ pqk,
    const float* __restrict__ bq, const float* __restrict__ bk,
    short* __restrict__ qb, short* __restrict__ kb, int KS)
{
    const int g   = blockIdx.y;
    const int idx = blockIdx.x * 256 + threadIdx.x;   // f32x4 index
    f32x4 s = (f32x4){0.f, 0.f, 0.f, 0.f};
    for (int z = 0; z < KS; ++z)
        s += *(const f32x4*)&pqk[(size_t)(z * 2 + g) * SEQ * HID + (size_t)idx * 4];
    const int n = (idx * 4) & (HID - 1);
    const float* bias = g ? bk : bq;
    s += *(const f32x4*)&bias[n];
    short* ob = g ? kb : qb;
    s16x4 o = (s16x4){f2bf(s[0]), f2bf(s[1]), f2bf(s[2]), f2bf(s[3])};
    *(s16x4*)&ob[(size_t)idx * 4] = o;
}

// ---------------------------------------------------------------------------
// Kernel 3: reduce transposed v partials + bias -> vtb bf16 [4096][240]
// ---------------------------------------------------------------------------
__global__ __launch_bounds__(256) void reduce_v(
    const float* __restrict__ pvt, const float* __restrict__ bv,
    short* __restrict__ vtb, int KS)
{
    const int idx = blockIdx.x * 256 + threadIdx.x;   // f32x4 index over [4096][240]
    f32x4 s = (f32x4){0.f, 0.f, 0.f, 0.f};
    for (int z = 0; z < KS; ++z)
        s += *(const f32x4*)&pvt[(size_t)z * HID * SEQ + (size_t)idx * 4];
    const int n = idx / 60;                           // 60 f32x4 per 240-row
    const float b = bv[n];
    s16x4 o = (s16x4){f2bf(s[0] + b), f2bf(s[1] + b), f2bf(s[2] + b), f2bf(s[3] + b)};
    *(s16x4*)&vtb[(size_t)idx * 4] = o;
}

// ---------------------------------------------------------------------------
// Kernel 4: scores + softmax.  4 waves/block, jt-split, LDS cross-wave
// softmax combine.  P^T stored bf16: ptb[h][j][i].
// ---------------------------------------------------------------------------
__global__ __launch_bounds__(256) void scores_kernel(
    const short* __restrict__ qb, const short* __restrict__ kb,
    short* __restrict__ ptb)
{
    const int it   = blockIdx.x;     // 0..14
    const int h    = blockIdx.y;     // 0..15
    const int tid  = threadIdx.x;
    const int lane = tid & 63;
    const int w    = tid >> 6;
    const int lr   = lane & 15;
    const int lg   = lane >> 4;
    const int jt0  = w * 4;
    const int NJT  = (w < 3) ? 4 : 3;

    __shared__ float redmax[4][16];
    __shared__ float redsum[4][16];

    f32x4 acc[4];
    #pragma unroll
    for (int j = 0; j < 4; ++j) acc[j] = (f32x4){0.f, 0.f, 0.f, 0.f};

    const int ib = it * 16;
    const short* qrow = &qb[(size_t)(ib + lr) * HID + h * HD + lg * 8];

    for (int d0 = 0; d0 < HD; d0 += 32) {
        s16x8 afr = *(const s16x8*)&qrow[d0];
        #pragma unroll
        for (int j = 0; j < 4; ++j) {
            if (j < NJT) {
                s16x8 bfr = *(const s16x8*)&kb[(size_t)((jt0 + j) * 16 + lr) * HID + h * HD + d0 + lg * 8];
                acc[j] = __builtin_amdgcn_mfma_f32_16x16x32_bf16(afr, bfr, acc[j], 0, 0, 0);
            }
        }
    }

    const float sc = 0.0625f;
    #pragma unroll
    for (int j = 0; j < 4; ++j) acc[j] *= sc;

    // phase 1: wave-local max per i, publish
    #pragma unroll
    for (int r = 0; r < 4; ++r) {
        float mx = -1e30f;
        #pragma unroll
        for (int j = 0; j < 4; ++j) if (j < NJT) mx = fmaxf(mx, acc[j][r]);
        #pragma unroll
        for (int s = 1; s < 16; s <<= 1) mx = fmaxf(mx, __shfl_xor(mx, s, 64));
        if (lr == 0) redmax[w][lg * 4 + r] = mx;
    }
    __syncthreads();
    // phase 2: global max, exp, wave-local sum, publish
    #pragma unroll
    for (int r = 0; r < 4; ++r) {
        const int i = lg * 4 + r;
        float mx = fmaxf(fmaxf(redmax[0][i], redmax[1][i]),
                         fmaxf(redmax[2][i], redmax[3][i]));
        float sum = 0.f;
        #pragma unroll
        for (int j = 0; j < 4; ++j) {
            if (j < NJT) {
                float e = expf(acc[j][r] - mx);
                acc[j][r] = e;
                sum += e;
            }
        }
        #pragma unroll
        for (int s = 1; s < 16; s <<= 1) sum += __shfl_xor(sum, s, 64);
        if (lr == 0) redsum[w][i] = sum;
    }
    __syncthreads();
    // phase 3: normalize + store bf16 (4 consecutive i per lane)
    #pragma unroll
    for (int r = 0; r < 4; ++r) {
        const int i = lg * 4 + r;
        const float inv = 1.f / (redsum[0][i] + redsum[1][i] + redsum[2][i] + redsum[3][i]);
        #pragma unroll
        for (int j = 0; j < 4; ++j) if (j < NJT) acc[j][r] *= inv;
    }
    #pragma unroll
    for (int j = 0; j < 4; ++j) {
        if (j < NJT) {
            const int jj = (jt0 + j) * 16 + lr;
            s16x4 o = (s16x4){f2bf(acc[j][0]), f2bf(acc[j][1]), f2bf(acc[j][2]), f2bf(acc[j][3])};
            *(s16x4*)&ptb[(size_t)(h * SEQ + jj) * SEQ + ib + lg * 4] = o;
        }
    }
}

// ---------------------------------------------------------------------------
// Kernel 5: O = P^T V per head, 4 waves/block jt-split, all-bf16 inputs.
// ---------------------------------------------------------------------------
__global__ __launch_bounds__(256) void pv_kernel(
    const short* __restrict__ ptb, const short* __restrict__ vtb,
    float* __restrict__ out)
{
    const int dt   = blockIdx.x;     // 0..15
    const int h    = blockIdx.y;
    const int tid  = threadIdx.x;
    const int lane = tid & 63;
    const int w    = tid >> 6;
    const int lr   = lane & 15;
    const int lg   = lane >> 4;
    const int NJT  = (w < 3) ? 4 : 3;

    f32x4 acc[4];
    #pragma unroll
    for (int j = 0; j < 4; ++j) acc[j] = (f32x4){0.f, 0.f, 0.f, 0.f};

    const short* vrow = &vtb[(size_t)(h * HD + dt * 16 + lr) * SEQ + lg * 8];

    for (int i0 = 0; i0 < 256; i0 += 32) {
        const bool ok = (i0 + lg * 8) < SEQ;
        s16x8 bfr = (s16x8){0,0,0,0,0,0,0,0};
        if (ok) bfr = *(const s16x8*)&vrow[i0];
        #pragma unroll
        for (int j = 0; j < 4; ++j) {
            if (j < NJT) {
                const int jt = w + j * 4;
                s16x8 afr = (s16x8){0,0,0,0,0,0,0,0};
                if (ok) afr = *(const s16x8*)&ptb[(size_t)(h * SEQ + jt * 16 + lr) * SEQ + i0 + lg * 8];
                acc[j] = __builtin_amdgcn_mfma_f32_16x16x32_bf16(afr, bfr, acc[j], 0, 0, 0);
            }
        }
    }

    #pragma unroll
    for (int j = 0; j < 4; ++j) {
        if (j < NJT) {
            const int jt = w + j * 4;
            #pragma unroll
            for (int r = 0; r < 4; ++r)
                out[(size_t)(jt * 16 + lg * 4 + r) * HID + h * HD + dt * 16 + lr] = acc[j][r];
        }
    }
}

extern "C" void kernel_launch(void* const* d_in, const int* in_sizes, int n_in,
                              void* d_out, int out_size, void* d_ws, size_t ws_size,
                              hipStream_t stream) {
    const float* in1 = (const float*)d_in[0];
    const float* in2 = (const float*)d_in[1];
    const float* Wq  = (const float*)d_in[2];
    const float* bq  = (const float*)d_in[3];
    const float* Wk  = (const float*)d_in[4];
    const float* bk  = (const float*)d_in[5];
    const float* Wv  = (const float*)d_in[6];
    const float* bv  = (const float*)d_in[7];
    float* out = (float*)d_out;

    char* w = (char*)d_ws;
    short* A1  = (short*)w;  w += (size_t)256 * HID * 2;        // 2 MB
    short* A2  = (short*)w;  w += (size_t)256 * HID * 2;        // 2 MB
    short* qb  = (short*)w;  w += (size_t)SEQ * HID * 2;        // 1.97 MB
    short* kb  = (short*)w;  w += (size_t)SEQ * HID * 2;
    short* vtb = (short*)w;  w += (size_t)HID * SEQ * 2;
    short* ptb = (short*)w;  w += (size_t)NH * SEQ * SEQ * 2;   // 1.84 MB
    float* pqk = (float*)w;
    const size_t fixed  = (size_t)(w - (char*)d_ws);
    const size_t perKS  = ((size_t)2 * SEQ * HID + (size_t)HID * SEQ) * sizeof(float); // 11.8 MB

    int KS = 1;
    if (fixed + 4 * perKS <= ws_size)      KS = 4;
    else if (fixed + 2 * perKS <= ws_size) KS = 2;
    const int KC = HID / KS;
    float* pvt = pqk + (size_t)KS * 2 * SEQ * HID;

    cvt_kernel<<<dim3(512, 2), 256, 0, stream>>>(in1, in2, A1, A2);
    qkv_gemm<<<dim3(32, 6, KS), 256, 0, stream>>>(A1, A2, Wq, Wk, Wv, pqk, pvt, KC);
    reduce_qk<<<dim3(960, 2), 256, 0, stream>>>(pqk, bq, bk, qb, kb, KS);
    reduce_v<<<960, 256, 0, stream>>>(pvt, bv, vtb, KS);
    scores_kernel<<<dim3(15, 16), 256, 0, stream>>>(qb, kb, ptb);
    pv_kernel<<<dim3(16, 16), 256, 0, stream>>>(ptb, vtb, out);
}